// Round 6
// baseline (406.225 us; speedup 1.0000x reference)
//
#include <hip/hip_runtime.h>

typedef __bf16 bf16x8 __attribute__((ext_vector_type(8)));
typedef float f32x4 __attribute__((ext_vector_type(4)));

__device__ __forceinline__ unsigned short f2bf(float f) {
  unsigned u = __builtin_bit_cast(unsigned, f);
  u += 0x7FFF + ((u >> 16) & 1);   // RNE
  return (unsigned short)(u >> 16);
}

__device__ __forceinline__ void gload_lds16(const void* g, void* l) {
  __builtin_amdgcn_global_load_lds(
      (const __attribute__((address_space(1))) void*)g,
      (__attribute__((address_space(3))) void*)l, 16, 0, 0);
}

__device__ __forceinline__ __attribute__((always_inline)) void mfma16q(
    int MG, f32x4 (&acc)[8][4], const bf16x8 (&aF)[4], const bf16x8 (&bF)[4])
{
#pragma unroll
  for (int mi = 0; mi < 4; ++mi)
#pragma unroll
    for (int ni = 0; ni < 4; ++ni)
      acc[MG * 4 + mi][ni] = __builtin_amdgcn_mfma_f32_16x16x32_bf16(
          aF[mi], bF[ni], acc[MG * 4 + mi][ni], 0, 0, 0);
}

// ---------------------------------------------------------------------------
// 256x256 GEMM C = A @ Bt^T (bf16 in, fp32 acc), m201-faithful quadrant phases.
// 8 waves (2M x 4N), BK=64, MFMA 16x16x32.
// LDS: 9-slot ring x 16KB chunks (144KB). Chunk = (A|B) row-half x K-tile
//   (128 rows x 64 K bf16), row-major [128][128B], byte-col ^ ((row&7)<<4).
// Per K-tile: 4 phases (kk,mgroup). Each phase: 4 A-frag ds_reads (+4 B on
//   mg==0, held in regs), stage ONE chunk (2 gload_lds, stage-ahead 5),
//   [q3: vmcnt(2), or vmcnt(0) near tail]; barrier; lgkmcnt(0); setprio(1);
//   16 MFMA; setprio(0); barrier.
// Ledger: in-order vmcnt retirement => vmcnt(2) at q3 certifies next tile's
//   4 chunks. Ring WAR: occupant C-9's reads end before bar2 of its q3;
//   stage of C issues after that bar2.
// OUTMODE 0: fp32 + bias[col]; 2: fp32 split-K partial (indexed by zt).
// ---------------------------------------------------------------------------
template <int OUTMODE>
__global__ __launch_bounds__(512, 2) void gemmq(
    const unsigned short* __restrict__ A, const unsigned short* __restrict__ Bt,
    void* __restrict__ Cv, const float* __restrict__ bias,
    int N, int K, int ldk, int gx, int gy, int nsplit,
    long sA, long sB, long sC)
{
  __shared__ alignas(16) unsigned char smem[147456];  // 9 x 16KB
  const int tid  = threadIdx.x;
  const int lane = tid & 63;
  const int wave = tid >> 6;
  const int waveM = wave >> 2;
  const int waveN = wave & 3;

  // bijective XCD swizzle (nwg % 8 == 0 for all launches here)
  const int nwg = (int)gridDim.x;
  const int cpx = nwg >> 3;
  const int wg  = (int)blockIdx.x;
  const int w   = (wg & 7) * cpx + (wg >> 3);
  const int x   = w % gx;
  const int rem = w / gx;
  const int y   = rem % gy;
  const int zt  = rem / gy;
  const int bz  = zt / nsplit;
  const int sp  = zt % nsplit;

  const int m0 = y * 256, n0 = x * 256;
  const size_t ldkB = (size_t)ldk * 2;
  const size_t ldkB64 = ldkB * 64, ldkB128 = ldkB * 128;

  // staging source (linear LDS dst o = tid*16 (+8192); inverse-swizzled src)
  const char* ApR;
  const char* BpR;
  {
    const char* Ab = (const char*)(A + (long)bz * sA + (long)sp * K) + (size_t)m0 * ldkB;
    const char* Bb = (const char*)(Bt + (long)bz * sB + (long)sp * K) + (size_t)n0 * ldkB;
    const int srow = tid >> 3;                                  // +64 for j=1 (same &7)
    const int scol = ((tid * 16) & 127) ^ ((srow & 7) << 4);
    ApR = Ab + (size_t)srow * ldkB + scol;
    BpR = Bb + (size_t)srow * ldkB + scol;
  }
  unsigned char* dst0 = smem + (unsigned)tid * 16;

  // per-lane ds_read offset components
  const int rowb = (lane & 15) * 128;
  const int q16  = (lane >> 4) << 4;
  const int csw0 = q16 ^ ((lane & 7) << 4);
  const int csw1 = (64 + q16) ^ ((lane & 7) << 4);
  const int bhalf = (waveN & 1) * 8192;

  f32x4 acc[8][4] = {};
  bf16x8 bF[4];   // persists mg0 -> mg1 within a kk

  const int nk = K >> 6;

  // ---- prologue: chunks 0..4 -> slots 0..4 (A0,A1,B0,B1 of t0; A0 of t1)
  gload_lds16(ApR,                     dst0 + 0 * 16384);
  gload_lds16(ApR + ldkB64,            dst0 + 0 * 16384 + 8192);
  gload_lds16(ApR + ldkB128,           dst0 + 1 * 16384);
  gload_lds16(ApR + ldkB128 + ldkB64,  dst0 + 1 * 16384 + 8192);
  gload_lds16(BpR,                     dst0 + 2 * 16384);
  gload_lds16(BpR + ldkB64,            dst0 + 2 * 16384 + 8192);
  gload_lds16(BpR + ldkB128,           dst0 + 3 * 16384);
  gload_lds16(BpR + ldkB128 + ldkB64,  dst0 + 3 * 16384 + 8192);
  gload_lds16(ApR + 128,               dst0 + 4 * 16384);
  gload_lds16(ApR + 128 + ldkB64,      dst0 + 4 * 16384 + 8192);
  asm volatile("s_waitcnt vmcnt(2)" ::: "memory");
  __builtin_amdgcn_sched_barrier(0);
  __builtin_amdgcn_s_barrier();

  int rs = 0, ss = 5;
  for (int kt = 0; kt < nk; ++kt) {
    int slotA = rs + waveM;              if (slotA >= 9) slotA -= 9;
    int slotB = rs + 2 + (waveN >> 1);   if (slotB >= 9) slotB -= 9;
    const unsigned char* aB0 = smem + slotA * 16384 + rowb + csw0;
    const unsigned char* aB1 = smem + slotA * 16384 + rowb + csw1;
    const unsigned char* bB0 = smem + slotB * 16384 + bhalf + rowb + csw0;
    const unsigned char* bB1 = smem + slotB * 16384 + bhalf + rowb + csw1;
    const size_t kb1 = (size_t)(kt + 1) * 128;
    const bool st012 = kt < nk - 1;
    const bool st3   = kt < nk - 2;
    bf16x8 aF[4];

    // ---- phase 0: kk0 mg0; read B(kk0); stage A1 of tile kt+1
#pragma unroll
    for (int mi = 0; mi < 4; ++mi) aF[mi] = *(const bf16x8*)(aB0 + mi * 2048);
#pragma unroll
    for (int ni = 0; ni < 4; ++ni) bF[ni] = *(const bf16x8*)(bB0 + ni * 2048);
    if (st012) {
      const char* g = ApR + ldkB128 + kb1;
      unsigned char* d = dst0 + ss * 16384;
      gload_lds16(g, d); gload_lds16(g + ldkB64, d + 8192);
    }
    ss = (ss == 8) ? 0 : ss + 1;
    __builtin_amdgcn_sched_barrier(0);
    __builtin_amdgcn_s_barrier();
    asm volatile("s_waitcnt lgkmcnt(0)" ::: "memory");
    __builtin_amdgcn_sched_barrier(0);
    __builtin_amdgcn_s_setprio(1);
    mfma16q(0, acc, aF, bF);
    __builtin_amdgcn_s_setprio(0);
    __builtin_amdgcn_s_barrier();

    // ---- phase 1: kk0 mg1; stage B0 of tile kt+1
#pragma unroll
    for (int mi = 0; mi < 4; ++mi) aF[mi] = *(const bf16x8*)(aB0 + 8192 + mi * 2048);
    if (st012) {
      const char* g = BpR + kb1;
      unsigned char* d = dst0 + ss * 16384;
      gload_lds16(g, d); gload_lds16(g + ldkB64, d + 8192);
    }
    ss = (ss == 8) ? 0 : ss + 1;
    __builtin_amdgcn_sched_barrier(0);
    __builtin_amdgcn_s_barrier();
    asm volatile("s_waitcnt lgkmcnt(0)" ::: "memory");
    __builtin_amdgcn_sched_barrier(0);
    __builtin_amdgcn_s_setprio(1);
    mfma16q(1, acc, aF, bF);
    __builtin_amdgcn_s_setprio(0);
    __builtin_amdgcn_s_barrier();

    // ---- phase 2: kk1 mg0; read B(kk1); stage B1 of tile kt+1
#pragma unroll
    for (int mi = 0; mi < 4; ++mi) aF[mi] = *(const bf16x8*)(aB1 + mi * 2048);
#pragma unroll
    for (int ni = 0; ni < 4; ++ni) bF[ni] = *(const bf16x8*)(bB1 + ni * 2048);
    if (st012) {
      const char* g = BpR + ldkB128 + kb1;
      unsigned char* d = dst0 + ss * 16384;
      gload_lds16(g, d); gload_lds16(g + ldkB64, d + 8192);
    }
    ss = (ss == 8) ? 0 : ss + 1;
    __builtin_amdgcn_sched_barrier(0);
    __builtin_amdgcn_s_barrier();
    asm volatile("s_waitcnt lgkmcnt(0)" ::: "memory");
    __builtin_amdgcn_sched_barrier(0);
    __builtin_amdgcn_s_setprio(1);
    mfma16q(0, acc, aF, bF);
    __builtin_amdgcn_s_setprio(0);
    __builtin_amdgcn_s_barrier();

    // ---- phase 3: kk1 mg1; stage A0 of tile kt+2; vmcnt certifies tile kt+1
#pragma unroll
    for (int mi = 0; mi < 4; ++mi) aF[mi] = *(const bf16x8*)(aB1 + 8192 + mi * 2048);
    if (st3) {
      const char* g = ApR + kb1 + 128;
      unsigned char* d = dst0 + ss * 16384;
      gload_lds16(g, d); gload_lds16(g + ldkB64, d + 8192);
    }
    ss = (ss == 8) ? 0 : ss + 1;
    if (kt < nk - 2) { asm volatile("s_waitcnt vmcnt(2)" ::: "memory"); }
    else            { asm volatile("s_waitcnt vmcnt(0)" ::: "memory"); }
    __builtin_amdgcn_sched_barrier(0);
    __builtin_amdgcn_s_barrier();
    asm volatile("s_waitcnt lgkmcnt(0)" ::: "memory");
    __builtin_amdgcn_sched_barrier(0);
    __builtin_amdgcn_s_setprio(1);
    mfma16q(1, acc, aF, bF);
    __builtin_amdgcn_s_setprio(0);
    __builtin_amdgcn_s_barrier();

    rs += 4; if (rs >= 9) rs -= 9;
  }

  // epilogue
  const int rb = (lane >> 4) * 4;
  const int cb_ = lane & 15;
  const long zout = (OUTMODE == 2) ? (long)zt : (long)bz;
#pragma unroll
  for (int m = 0; m < 8; ++m) {
#pragma unroll
    for (int n = 0; n < 4; ++n) {
      const int col = n0 + waveN * 64 + n * 16 + cb_;
      const float badd = (OUTMODE == 0) ? bias[col] : 0.f;
#pragma unroll
      for (int r = 0; r < 4; ++r) {
        const int row = m0 + waveM * 128 + m * 16 + rb + r;
        ((float*)Cv)[zout * sC + (size_t)row * N + col] = acc[m][n][r] + badd;
      }
    }
  }
}

// ---------------------------------------------------------------------------
// split-K reduce: out[b][i] = bf16(sum_{s<4} P[b*4+s][i]), slices 1024x1024
// ---------------------------------------------------------------------------
__global__ __launch_bounds__(256) void red4(
    const float* __restrict__ P, unsigned short* __restrict__ O)
{
  const int i = blockIdx.x * 256 + threadIdx.x;
  const int b = i >> 18;
  const int j = i & 262143;
  const float4 v0 = ((const float4*)(P + (((long)(b * 4 + 0)) << 20)))[j];
  const float4 v1 = ((const float4*)(P + (((long)(b * 4 + 1)) << 20)))[j];
  const float4 v2 = ((const float4*)(P + (((long)(b * 4 + 2)) << 20)))[j];
  const float4 v3 = ((const float4*)(P + (((long)(b * 4 + 3)) << 20)))[j];
  unsigned short o4[4] = {
    f2bf(v0.x + v1.x + v2.x + v3.x), f2bf(v0.y + v1.y + v2.y + v3.y),
    f2bf(v0.z + v1.z + v2.z + v3.z), f2bf(v0.w + v1.w + v2.w + v3.w)};
  ((uint2*)(O + ((long)b << 20)))[j] = *(const uint2*)o4;
}

// ---------------------------------------------------------------------------
__global__ __launch_bounds__(256) void conv_bf16(
    const float* __restrict__ in, unsigned short* __restrict__ out, int n4)
{
  int i = blockIdx.x * 256 + threadIdx.x;
  if (i < n4) {
    float4 v = ((const float4*)in)[i];
    unsigned short o4[4] = {f2bf(v.x), f2bf(v.y), f2bf(v.z), f2bf(v.w)};
    ((uint2*)out)[i] = *(const uint2*)o4;
  }
}

// ---------------------------------------------------------------------------
__global__ __launch_bounds__(256) void row_softmax(
    const float* __restrict__ S, unsigned short* __restrict__ O)
{
  const int row = blockIdx.x;
  const int tid = threadIdx.x;
  const float4 v = ((const float4*)(S + (size_t)row * 1024))[tid];
  float m = fmaxf(fmaxf(v.x, v.y), fmaxf(v.z, v.w));
#pragma unroll
  for (int o = 32; o >= 1; o >>= 1) m = fmaxf(m, __shfl_xor(m, o));
  __shared__ float rm[4], rs[4];
  const int w = tid >> 6;
  if ((tid & 63) == 0) rm[w] = m;
  __syncthreads();
  m = fmaxf(fmaxf(rm[0], rm[1]), fmaxf(rm[2], rm[3]));
  const float e0 = __expf(v.x - m), e1 = __expf(v.y - m);
  const float e2 = __expf(v.z - m), e3 = __expf(v.w - m);
  float s = e0 + e1 + e2 + e3;
#pragma unroll
  for (int o = 32; o >= 1; o >>= 1) s += __shfl_xor(s, o);
  if ((tid & 63) == 0) rs[w] = s;
  __syncthreads();
  s = rs[0] + rs[1] + rs[2] + rs[3];
  const float inv = 1.f / s;
  unsigned short o4[4] = {f2bf(e0 * inv), f2bf(e1 * inv), f2bf(e2 * inv), f2bf(e3 * inv)};
  ((uint2*)(O + (size_t)row * 1024))[tid] = *(const uint2*)o4;
}

// ---------------------------------------------------------------------------
__global__ __launch_bounds__(256) void col_sum(
    const float* __restrict__ S, float* __restrict__ psum)
{
  const int d = blockIdx.x * 256 + threadIdx.x;
  const int slab = blockIdx.y;
  const int b = blockIdx.z;
  const float* p = S + ((size_t)b * 4096 + (size_t)slab * 64) * 1024 + d;
  float acc[8] = {};
#pragma unroll
  for (int i = 0; i < 8; ++i) {
    float x[8];
#pragma unroll
    for (int j = 0; j < 8; ++j) x[j] = p[(size_t)(i * 8 + j) * 1024];
#pragma unroll
    for (int j = 0; j < 8; ++j) acc[j] += __expf(x[j]);
  }
  const float s = ((acc[0] + acc[1]) + (acc[2] + acc[3])) +
                  ((acc[4] + acc[5]) + (acc[6] + acc[7]));
  psum[((size_t)b * 64 + slab) * 1024 + d] = s;
}

__global__ __launch_bounds__(256) void col_inv(
    const float* __restrict__ psum, float* __restrict__ si)
{
  const int d = blockIdx.x * 256 + threadIdx.x;
  const int b = blockIdx.y;
  float s = 0.f;
#pragma unroll
  for (int i = 0; i < 64; ++i) s += psum[((size_t)b * 64 + i) * 1024 + d];
  si[b * 1024 + d] = 1.f / s;
}

// ---------------------------------------------------------------------------
__global__ __launch_bounds__(256) void col_norm_tr(
    const float* __restrict__ S, const float* __restrict__ sinv,
    unsigned short* __restrict__ T)
{
  __shared__ unsigned short tile[64][73];
  __shared__ float sl[64];
  const int l0 = blockIdx.x * 64;
  const int d0 = blockIdx.y * 64;
  const int b  = blockIdx.z;
  const int tid = threadIdx.x;
  if (tid < 64) sl[tid] = sinv[b * 1024 + d0 + tid];
  __syncthreads();
  const int r = tid >> 2;
  const int cq = (tid & 3) * 16;
  const float* Sb = S + ((size_t)b * 4096 + l0 + r) * 1024 + d0;
#pragma unroll
  for (int i = 0; i < 4; ++i) {
    const int c = cq + i * 4;
    const float4 v = *(const float4*)&Sb[c];
    tile[r][c + 0] = f2bf(__expf(v.x) * sl[c + 0]);
    tile[r][c + 1] = f2bf(__expf(v.y) * sl[c + 1]);
    tile[r][c + 2] = f2bf(__expf(v.z) * sl[c + 2]);
    tile[r][c + 3] = f2bf(__expf(v.w) * sl[c + 3]);
  }
  __syncthreads();
  const int c = tid >> 2;
  const int rq = (tid & 3) * 16;
  unsigned short outv[16];
#pragma unroll
  for (int j = 0; j < 16; ++j) outv[j] = tile[rq + j][c];
  unsigned short* Tb = T + ((size_t)b * 1024 + d0 + c) * 4096 + l0 + rq;
  ((uint4*)Tb)[0] = ((const uint4*)outv)[0];
  ((uint4*)Tb)[1] = ((const uint4*)outv)[1];
}

// ---------------------------------------------------------------------------
__global__ __launch_bounds__(256) void w_tr(
    const float* __restrict__ W, unsigned short* __restrict__ WT)
{
  __shared__ unsigned short tile[64][73];
  const int c0 = blockIdx.x * 64;
  const int r0 = blockIdx.y * 64;
  const int tid = threadIdx.x;
  const int r = tid >> 2;
  const int cq = (tid & 3) * 16;
#pragma unroll
  for (int i = 0; i < 4; ++i) {
    const int c = cq + i * 4;
    const float4 v = *(const float4*)&W[(size_t)(r0 + r) * 1024 + c0 + c];
    tile[r][c + 0] = f2bf(v.x);
    tile[r][c + 1] = f2bf(v.y);
    tile[r][c + 2] = f2bf(v.z);
    tile[r][c + 3] = f2bf(v.w);
  }
  __syncthreads();
  const int c = tid >> 2;
  const int rq = (tid & 3) * 16;
  unsigned short outv[16];
#pragma unroll
  for (int j = 0; j < 16; ++j) outv[j] = tile[rq + j][c];
  unsigned short* Tb = WT + (size_t)(c0 + c) * 1024 + r0 + rq;
  ((uint4*)Tb)[0] = ((const uint4*)outv)[0];
  ((uint4*)Tb)[1] = ((const uint4*)outv)[1];
}

// ---------------------------------------------------------------------------
extern "C" void kernel_launch(void* const* d_in, const int* in_sizes, int n_in,
                              void* d_out, int out_size, void* d_ws, size_t ws_size,
                              hipStream_t stream) {
  const float* q  = (const float*)d_in[0];
  const float* k  = (const float*)d_in[1];
  const float* v  = (const float*)d_in[2];
  const float* Wq = (const float*)d_in[3];
  const float* bq = (const float*)d_in[4];
  const float* Wk = (const float*)d_in[5];
  const float* bk = (const float*)d_in[6];
  const float* Wv = (const float*)d_in[7];
  const float* bv = (const float*)d_in[8];
  const float* Wo = (const float*)d_in[9];
  const float* bo = (const float*)d_in[10];
  float* out = (float*)d_out;

  // workspace layout (~201 MB)
  char* p = (char*)d_ws;
  unsigned short* Xbf = (unsigned short*)p;  p += 33554432;       // bf16 [16384][1024]; later M, GT
  unsigned short* WqT = (unsigned short*)p;  p += 2097152;
  unsigned short* WkT = (unsigned short*)p;  p += 2097152;
  unsigned short* WvT = (unsigned short*)p;  p += 2097152;
  unsigned short* WoT = (unsigned short*)p;  p += 2097152;
  char* Sreg = p;                            p += 67108864;       // fp32 S; later split-K partials
  float* S = (float*)Sreg;
  float* Part = (float*)Sreg;                                     // alias (S dead)
  unsigned short* Mbf = Xbf;                                      // [B][1024][1024] (Xbf dead)
  unsigned short* GTbf = Xbf + 4L * 1024 * 1024;                  // [B][1024][1024]
  unsigned short* Qp  = (unsigned short*)p;  p += 33554432;
  unsigned short* KpT = (unsigned short*)p;  p += 33554432;       // [B][1024][4096]
  unsigned short* VpT = (unsigned short*)p;  p += 33554432;
  float* psum = (float*)p; p += 4 * 64 * 1024 * 4;
  float* sinv = (float*)p; p += 4 * 1024 * 4;

  const dim3 blk(256);
  const dim3 blk512(512);
  const int N4 = 16777216 / 4;

  // weights -> bf16 transposed
  w_tr<<<dim3(16, 16), blk, 0, stream>>>(Wq, WqT);
  w_tr<<<dim3(16, 16), blk, 0, stream>>>(Wk, WkT);
  w_tr<<<dim3(16, 16), blk, 0, stream>>>(Wv, WvT);
  w_tr<<<dim3(16, 16), blk, 0, stream>>>(Wo, WoT);

  // ---- Q path: S = q@Wq + bq ; Qp = row-softmax(S)
  conv_bf16<<<16384, blk, 0, stream>>>(q, Xbf, N4);
  gemmq<0><<<256, blk512, 0, stream>>>(Xbf, WqT, S, bq, 1024, 1024, 1024, 4, 64, 1, 0, 0, 0);
  row_softmax<<<16384, blk, 0, stream>>>(S, Qp);

  // ---- K path: S = k@Wk + bk ; KpT = col-softmax(S)^T
  conv_bf16<<<16384, blk, 0, stream>>>(k, Xbf, N4);
  gemmq<0><<<256, blk512, 0, stream>>>(Xbf, WkT, S, bk, 1024, 1024, 1024, 4, 64, 1, 0, 0, 0);
  col_sum<<<dim3(4, 64, 4), blk, 0, stream>>>(S, psum);
  col_inv<<<dim3(4, 4), blk, 0, stream>>>(psum, sinv);
  col_norm_tr<<<dim3(64, 16, 4), blk, 0, stream>>>(S, sinv, KpT);

  // ---- V path
  conv_bf16<<<16384, blk, 0, stream>>>(v, Xbf, N4);
  gemmq<0><<<256, blk512, 0, stream>>>(Xbf, WvT, S, bv, 1024, 1024, 1024, 4, 64, 1, 0, 0, 0);
  col_sum<<<dim3(4, 64, 4), blk, 0, stream>>>(S, psum);
  col_inv<<<dim3(4, 4), blk, 0, stream>>>(psum, sinv);
  col_norm_tr<<<dim3(64, 16, 4), blk, 0, stream>>>(S, sinv, VpT);

  // ---- M_b = Kp^T Vp : partials P[b*4+s] = KpT_chunk @ VpT_chunk^T, K=4x1024
  gemmq<2><<<256, blk512, 0, stream>>>(KpT, VpT, Part, nullptr,
      1024, 1024, 4096, 4, 4, 4, 1024L * 4096, 1024L * 4096, 1024L * 1024);
  red4<<<4096, blk, 0, stream>>>(Part, Mbf);

  // ---- GT_b = (M_b @ Wo)^T = WoT @ M_b^T : split-K x4 over K=1024
  gemmq<2><<<256, blk512, 0, stream>>>(WoT, Mbf, Part, nullptr,
      1024, 256, 1024, 4, 4, 4, 0, 1024L * 1024, 1024L * 1024);
  red4<<<4096, blk, 0, stream>>>(Part, GTbf);

  // ---- Out_b = Qp_b @ GT_b^T + bo  (= Qp M Wo + bo = ctx@Wo + bo)
  gemmq<0><<<256, blk512, 0, stream>>>(Qp, GTbf, out, bo,
      1024, 1024, 1024, 4, 16, 1, 4096L * 1024, 1024L * 1024, 4096L * 1024);

  (void)in_sizes; (void)n_in; (void)out_size; (void)ws_size;
}

// Round 7
// 366.909 us; speedup vs baseline: 1.1072x; 1.1072x over previous
//
#include <hip/hip_runtime.h>

typedef __bf16 bf16x8 __attribute__((ext_vector_type(8)));
typedef float f32x4 __attribute__((ext_vector_type(4)));

__device__ __forceinline__ unsigned short f2bf(float f) {
  unsigned u = __builtin_bit_cast(unsigned, f);
  u += 0x7FFF + ((u >> 16) & 1);   // RNE
  return (unsigned short)(u >> 16);
}
__device__ __forceinline__ float h2f(unsigned short h) {
  return (float)__builtin_bit_cast(_Float16, h);
}
__device__ __forceinline__ unsigned short f2h(float f) {
  return __builtin_bit_cast(unsigned short, (_Float16)f);
}

__device__ __forceinline__ void gload_lds16(const void* g, void* l) {
  __builtin_amdgcn_global_load_lds(
      (const __attribute__((address_space(1))) void*)g,
      (__attribute__((address_space(3))) void*)l, 16, 0, 0);
}

// ---------------------------------------------------------------------------
// 128x256 tile GEMM, C = A @ Bt^T (bf16 in, fp32 acc). High-TLP variant:
// single 48KB LDS buffer -> 2 blocks/CU resident (cross-block stall overlap,
// the m97 mechanism), 8 waves (2M x 4N), per-wave 64x64 (acc 4x4xf32x4 = 64
// regs), __launch_bounds__(512,4) caps VGPR at 128 for 16 waves/CU.
// Plain __syncthreads loop: stage 6 gload_lds -> sync -> 2x(read+16 MFMA) ->
// sync. XOR-swizzled LDS (conflict-free b128), XCD-swizzled 1D grid.
// OUTMODE 0: fp32 + bias[col]; 2: fp32 split-K partial (indexed by zt);
//         3: fp16 exp(acc + bias[col])  (fused softmax numerator).
// ---------------------------------------------------------------------------
template <int OUTMODE>
__global__ __launch_bounds__(512, 4) void gemmt(
    const unsigned short* __restrict__ A, const unsigned short* __restrict__ Bt,
    void* __restrict__ Cv, const float* __restrict__ bias,
    int N, int K, int ldk, int gx, int gy, int nsplit,
    long sA, long sB, long sC)
{
  __shared__ alignas(16) unsigned char smem[49152];  // A 16KB | B 32KB
  const int tid  = threadIdx.x;
  const int lane = tid & 63;
  const int wave = tid >> 6;
  const int waveM = wave >> 2;      // 0..1 (64 rows each)
  const int waveN = wave & 3;       // 0..3 (64 cols each)

  // bijective XCD swizzle (nwg % 8 == 0 for all launches here)
  const int nwg = (int)gridDim.x;
  const int cpx = nwg >> 3;
  const int wg  = (int)blockIdx.x;
  const int w   = (wg & 7) * cpx + (wg >> 3);
  const int x   = w % gx;
  const int rem = w / gx;
  const int y   = rem % gy;
  const int zt  = rem / gy;
  const int bz  = zt / nsplit;
  const int sp  = zt % nsplit;

  const int m0 = y * 128, n0 = x * 256;
  const size_t ldkB = (size_t)ldk * 2;
  const size_t ldkB64 = ldkB * 64, ldkB128 = ldkB * 128;

  // staging: LDS dst linear (tid*16 within 8KB row-group); src inverse-swizzled
  const char* ApR;
  const char* BpR;
  {
    const char* Ab = (const char*)(A + (long)bz * sA + (long)sp * K) + (size_t)m0 * ldkB;
    const char* Bb = (const char*)(Bt + (long)bz * sB + (long)sp * K) + (size_t)n0 * ldkB;
    const int srow = tid >> 3;                       // 0..63 (row per 8 threads)
    const int scol = ((tid * 16) & 127) ^ ((srow & 7) << 4);
    ApR = Ab + (size_t)srow * ldkB + scol;
    BpR = Bb + (size_t)srow * ldkB + scol;
  }
  const unsigned oA0 = (unsigned)tid * 16;

  // ds_read byte offsets (kk=0); kk=1 offset = kk0 ^ 64 (XOR field is bits 4-6)
  int offA[4], offB[4];
  {
    const int q16 = (lane >> 4) << 4;
#pragma unroll
    for (int mi = 0; mi < 4; ++mi) {
      const int r = waveM * 64 + mi * 16 + (lane & 15);
      offA[mi] = r * 128 + (q16 ^ ((r & 7) << 4));
    }
#pragma unroll
    for (int ni = 0; ni < 4; ++ni) {
      const int r = waveN * 64 + ni * 16 + (lane & 15);
      offB[ni] = 16384 + r * 128 + (q16 ^ ((r & 7) << 4));
    }
  }

  f32x4 acc[4][4] = {};

  const int nk = K >> 6;
  for (int kt = 0; kt < nk; ++kt) {
    const size_t kb = (size_t)kt * 128;
    gload_lds16(ApR + kb,                     smem + oA0);
    gload_lds16(ApR + ldkB64 + kb,            smem + oA0 + 8192);
    gload_lds16(BpR + kb,                     smem + 16384 + oA0);
    gload_lds16(BpR + ldkB64 + kb,            smem + 16384 + oA0 + 8192);
    gload_lds16(BpR + ldkB128 + kb,           smem + 16384 + oA0 + 16384);
    gload_lds16(BpR + ldkB128 + ldkB64 + kb,  smem + 16384 + oA0 + 24576);
    __syncthreads();
#pragma unroll
    for (int kk = 0; kk < 2; ++kk) {
      const int kx = kk << 6;
      bf16x8 aF[4], bF[4];
#pragma unroll
      for (int mi = 0; mi < 4; ++mi) aF[mi] = *(const bf16x8*)&smem[offA[mi] ^ kx];
#pragma unroll
      for (int ni = 0; ni < 4; ++ni) bF[ni] = *(const bf16x8*)&smem[offB[ni] ^ kx];
#pragma unroll
      for (int mi = 0; mi < 4; ++mi)
#pragma unroll
        for (int ni = 0; ni < 4; ++ni)
          acc[mi][ni] = __builtin_amdgcn_mfma_f32_16x16x32_bf16(aF[mi], bF[ni], acc[mi][ni], 0, 0, 0);
    }
    __syncthreads();
  }

  // epilogue
  const int rb = (lane >> 4) * 4;
  const int cb_ = lane & 15;
  const long zout = (OUTMODE == 2) ? (long)zt : (long)bz;
#pragma unroll
  for (int m = 0; m < 4; ++m) {
#pragma unroll
    for (int n = 0; n < 4; ++n) {
      const int col = n0 + waveN * 64 + n * 16 + cb_;
      const float badd = (OUTMODE == 0 || OUTMODE == 3) ? bias[col] : 0.f;
#pragma unroll
      for (int r = 0; r < 4; ++r) {
        const int row = m0 + waveM * 64 + m * 16 + rb + r;
        const float vv = acc[m][n][r] + badd;
        if (OUTMODE == 3)
          ((unsigned short*)Cv)[zout * sC + (size_t)row * N + col] = f2h(__expf(vv));
        else
          ((float*)Cv)[zout * sC + (size_t)row * N + col] = vv;
      }
    }
  }
}

// ---------------------------------------------------------------------------
// split-K reduce: out[b][i] = bf16(sum_{s<4} P[b*4+s][i]), slices 1024x1024
// ---------------------------------------------------------------------------
__global__ __launch_bounds__(256) void red4(
    const float* __restrict__ P, unsigned short* __restrict__ O)
{
  const int i = blockIdx.x * 256 + threadIdx.x;
  const int b = i >> 18;
  const int j = i & 262143;
  const float4 v0 = ((const float4*)(P + (((long)(b * 4 + 0)) << 20)))[j];
  const float4 v1 = ((const float4*)(P + (((long)(b * 4 + 1)) << 20)))[j];
  const float4 v2 = ((const float4*)(P + (((long)(b * 4 + 2)) << 20)))[j];
  const float4 v3 = ((const float4*)(P + (((long)(b * 4 + 3)) << 20)))[j];
  unsigned short o4[4] = {
    f2bf(v0.x + v1.x + v2.x + v3.x), f2bf(v0.y + v1.y + v2.y + v3.y),
    f2bf(v0.z + v1.z + v2.z + v3.z), f2bf(v0.w + v1.w + v2.w + v3.w)};
  ((uint2*)(O + ((long)b << 20)))[j] = *(const uint2*)o4;
}

// ---------------------------------------------------------------------------
__global__ __launch_bounds__(256) void conv_bf16(
    const float* __restrict__ in, unsigned short* __restrict__ out, int n4)
{
  int i = blockIdx.x * 256 + threadIdx.x;
  if (i < n4) {
    float4 v = ((const float4*)in)[i];
    unsigned short o4[4] = {f2bf(v.x), f2bf(v.y), f2bf(v.z), f2bf(v.w)};
    ((uint2*)out)[i] = *(const uint2*)o4;
  }
}

// ---------------------------------------------------------------------------
// Row normalize of E=exp(S): Qp = E / rowsum(E), fp16 in -> bf16 out.
// One block (256 thr) per row of 1024.
// ---------------------------------------------------------------------------
__global__ __launch_bounds__(256) void row_norm_e(
    const unsigned short* __restrict__ E, unsigned short* __restrict__ O)
{
  const int row = blockIdx.x;
  const int tid = threadIdx.x;
  const uint2 u = ((const uint2*)(E + (size_t)row * 1024))[tid];
  const float e0 = h2f((unsigned short)(u.x & 0xffff));
  const float e1 = h2f((unsigned short)(u.x >> 16));
  const float e2 = h2f((unsigned short)(u.y & 0xffff));
  const float e3 = h2f((unsigned short)(u.y >> 16));
  float s = (e0 + e1) + (e2 + e3);
#pragma unroll
  for (int o = 32; o >= 1; o >>= 1) s += __shfl_xor(s, o);
  __shared__ float rs[4];
  if ((tid & 63) == 0) rs[tid >> 6] = s;
  __syncthreads();
  s = (rs[0] + rs[1]) + (rs[2] + rs[3]);
  const float inv = 1.f / s;
  unsigned short o4[4] = {f2bf(e0 * inv), f2bf(e1 * inv), f2bf(e2 * inv), f2bf(e3 * inv)};
  ((uint2*)(O + (size_t)row * 1024))[tid] = *(const uint2*)o4;
}

// ---------------------------------------------------------------------------
// Column partial sums of E (fp16): thread owns one column d in a 64-row slab;
// 8 independent accumulators. grid (D/256, L/64, B).
// ---------------------------------------------------------------------------
__global__ __launch_bounds__(256) void col_sum_e(
    const unsigned short* __restrict__ E, float* __restrict__ psum)
{
  const int d = blockIdx.x * 256 + threadIdx.x;
  const int slab = blockIdx.y;
  const int b = blockIdx.z;
  const unsigned short* p = E + ((size_t)b * 4096 + (size_t)slab * 64) * 1024 + d;
  float acc[8] = {};
#pragma unroll
  for (int i = 0; i < 8; ++i) {
    unsigned short x[8];
#pragma unroll
    for (int j = 0; j < 8; ++j) x[j] = p[(size_t)(i * 8 + j) * 1024];
#pragma unroll
    for (int j = 0; j < 8; ++j) acc[j] += h2f(x[j]);
  }
  const float s = ((acc[0] + acc[1]) + (acc[2] + acc[3])) +
                  ((acc[4] + acc[5]) + (acc[6] + acc[7]));
  psum[((size_t)b * 64 + slab) * 1024 + d] = s;
}

__global__ __launch_bounds__(256) void col_inv(
    const float* __restrict__ psum, float* __restrict__ si)
{
  const int d = blockIdx.x * 256 + threadIdx.x;
  const int b = blockIdx.y;
  float s = 0.f;
#pragma unroll
  for (int i = 0; i < 64; ++i) s += psum[((size_t)b * 64 + i) * 1024 + d];
  si[b * 1024 + d] = 1.f / s;
}

// ---------------------------------------------------------------------------
// Column normalize + transpose: T[b][d][l] = bf16(E[b][l][d] * sinv[d])
// grid (L/64, D/64, B), 64x64 LDS tile transpose. E fp16.
// ---------------------------------------------------------------------------
__global__ __launch_bounds__(256) void col_norm_tr_e(
    const unsigned short* __restrict__ E, const float* __restrict__ sinv,
    unsigned short* __restrict__ T)
{
  __shared__ unsigned short tile[64][73];
  __shared__ float sl[64];
  const int l0 = blockIdx.x * 64;
  const int d0 = blockIdx.y * 64;
  const int b  = blockIdx.z;
  const int tid = threadIdx.x;
  if (tid < 64) sl[tid] = sinv[b * 1024 + d0 + tid];
  __syncthreads();
  const int r = tid >> 2;
  const int cq = (tid & 3) * 16;
  const unsigned short* Eb = E + ((size_t)b * 4096 + l0 + r) * 1024 + d0;
#pragma unroll
  for (int i = 0; i < 4; ++i) {
    const int c = cq + i * 4;
    const uint2 u = *(const uint2*)&Eb[c];
    tile[r][c + 0] = f2bf(h2f((unsigned short)(u.x & 0xffff)) * sl[c + 0]);
    tile[r][c + 1] = f2bf(h2f((unsigned short)(u.x >> 16))    * sl[c + 1]);
    tile[r][c + 2] = f2bf(h2f((unsigned short)(u.y & 0xffff)) * sl[c + 2]);
    tile[r][c + 3] = f2bf(h2f((unsigned short)(u.y >> 16))    * sl[c + 3]);
  }
  __syncthreads();
  const int c = tid >> 2;
  const int rq = (tid & 3) * 16;
  unsigned short outv[16];
#pragma unroll
  for (int j = 0; j < 16; ++j) outv[j] = tile[rq + j][c];
  unsigned short* Tb = T + ((size_t)b * 1024 + d0 + c) * 4096 + l0 + rq;
  ((uint4*)Tb)[0] = ((const uint4*)outv)[0];
  ((uint4*)Tb)[1] = ((const uint4*)outv)[1];
}

// ---------------------------------------------------------------------------
__global__ __launch_bounds__(256) void w_tr(
    const float* __restrict__ W, unsigned short* __restrict__ WT)
{
  __shared__ unsigned short tile[64][73];
  const int c0 = blockIdx.x * 64;
  const int r0 = blockIdx.y * 64;
  const int tid = threadIdx.x;
  const int r = tid >> 2;
  const int cq = (tid & 3) * 16;
#pragma unroll
  for (int i = 0; i < 4; ++i) {
    const int c = cq + i * 4;
    const float4 v = *(const float4*)&W[(size_t)(r0 + r) * 1024 + c0 + c];
    tile[r][c + 0] = f2bf(v.x);
    tile[r][c + 1] = f2bf(v.y);
    tile[r][c + 2] = f2bf(v.z);
    tile[r][c + 3] = f2bf(v.w);
  }
  __syncthreads();
  const int c = tid >> 2;
  const int rq = (tid & 3) * 16;
  unsigned short outv[16];
#pragma unroll
  for (int j = 0; j < 16; ++j) outv[j] = tile[rq + j][c];
  unsigned short* Tb = WT + (size_t)(c0 + c) * 1024 + r0 + rq;
  ((uint4*)Tb)[0] = ((const uint4*)outv)[0];
  ((uint4*)Tb)[1] = ((const uint4*)outv)[1];
}

// ---------------------------------------------------------------------------
extern "C" void kernel_launch(void* const* d_in, const int* in_sizes, int n_in,
                              void* d_out, int out_size, void* d_ws, size_t ws_size,
                              hipStream_t stream) {
  const float* q  = (const float*)d_in[0];
  const float* k  = (const float*)d_in[1];
  const float* v  = (const float*)d_in[2];
  const float* Wq = (const float*)d_in[3];
  const float* bq = (const float*)d_in[4];
  const float* Wk = (const float*)d_in[5];
  const float* bk = (const float*)d_in[6];
  const float* Wv = (const float*)d_in[7];
  const float* bv = (const float*)d_in[8];
  const float* Wo = (const float*)d_in[9];
  const float* bo = (const float*)d_in[10];
  float* out = (float*)d_out;

  // workspace layout (~201 MB)
  char* p = (char*)d_ws;
  unsigned short* Xbf = (unsigned short*)p;  p += 33554432;       // bf16 [16384][1024]; later Mbf, GTbf
  unsigned short* WqT = (unsigned short*)p;  p += 2097152;
  unsigned short* WkT = (unsigned short*)p;  p += 2097152;
  unsigned short* WvT = (unsigned short*)p;  p += 2097152;
  unsigned short* WoT = (unsigned short*)p;  p += 2097152;
  char* Sreg = p;                            p += 67108864;       // E fp16 [16384][1024]; later split-K partials fp32
  unsigned short* E = (unsigned short*)Sreg;
  float* Part = (float*)Sreg;                                     // alias (E dead when Part written)
  unsigned short* Mbf = Xbf;                                      // [B][1024][1024] (Xbf dead)
  unsigned short* GTbf = Xbf + 4L * 1024 * 1024;                  // [B][1024][1024]
  unsigned short* Qp  = (unsigned short*)p;  p += 33554432;
  unsigned short* KpT = (unsigned short*)p;  p += 33554432;       // [B][1024][4096]
  unsigned short* VpT = (unsigned short*)p;  p += 33554432;
  float* psum = (float*)p; p += 4 * 64 * 1024 * 4;
  float* sinv = (float*)p; p += 4 * 1024 * 4;

  const dim3 blk(256);
  const dim3 blk512(512);
  const int N4 = 16777216 / 4;

  // weights -> bf16 transposed
  w_tr<<<dim3(16, 16), blk, 0, stream>>>(Wq, WqT);
  w_tr<<<dim3(16, 16), blk, 0, stream>>>(Wk, WkT);
  w_tr<<<dim3(16, 16), blk, 0, stream>>>(Wv, WvT);
  w_tr<<<dim3(16, 16), blk, 0, stream>>>(Wo, WoT);

  // ---- Q path: E = exp(q@Wq + bq) ; Qp = E / rowsum
  conv_bf16<<<16384, blk, 0, stream>>>(q, Xbf, N4);
  gemmt<3><<<512, blk512, 0, stream>>>(Xbf, WqT, E, bq, 1024, 1024, 1024, 4, 128, 1, 0, 0, 0);
  row_norm_e<<<16384, blk, 0, stream>>>(E, Qp);

  // ---- K path: E = exp(k@Wk + bk) ; KpT = (E / colsum)^T
  conv_bf16<<<16384, blk, 0, stream>>>(k, Xbf, N4);
  gemmt<3><<<512, blk512, 0, stream>>>(Xbf, WkT, E, bk, 1024, 1024, 1024, 4, 128, 1, 0, 0, 0);
  col_sum_e<<<dim3(4, 64, 4), blk, 0, stream>>>(E, psum);
  col_inv<<<dim3(4, 4), blk, 0, stream>>>(psum, sinv);
  col_norm_tr_e<<<dim3(64, 16, 4), blk, 0, stream>>>(E, sinv, KpT);

  // ---- V path
  conv_bf16<<<16384, blk, 0, stream>>>(v, Xbf, N4);
  gemmt<3><<<512, blk512, 0, stream>>>(Xbf, WvT, E, bv, 1024, 1024, 1024, 4, 128, 1, 0, 0, 0);
  col_sum_e<<<dim3(4, 64, 4), blk, 0, stream>>>(E, psum);
  col_inv<<<dim3(4, 4), blk, 0, stream>>>(psum, sinv);
  col_norm_tr_e<<<dim3(64, 16, 4), blk, 0, stream>>>(E, sinv, VpT);

  // ---- M_b = Kp^T Vp : partials P[b*4+s] = KpT_chunk @ VpT_chunk^T, K=4x1024
  gemmt<2><<<512, blk512, 0, stream>>>(KpT, VpT, Part, nullptr,
      1024, 1024, 4096, 4, 8, 4, 1024L * 4096, 1024L * 4096, 1024L * 1024);
  red4<<<4096, blk, 0, stream>>>(Part, Mbf);

  // ---- GT_b = (M_b @ Wo)^T = WoT @ M_b^T : split-K x4 over K=1024
  gemmt<2><<<512, blk512, 0, stream>>>(WoT, Mbf, Part, nullptr,
      1024, 256, 1024, 4, 8, 4, 0, 1024L * 1024, 1024L * 1024);
  red4<<<4096, blk, 0, stream>>>(Part, GTbf);

  // ---- Out_b = Qp_b @ GT_b^T + bo  (= Qp M Wo + bo = ctx@Wo + bo)
  gemmt<0><<<512, blk512, 0, stream>>>(Qp, GTbf, out, bo,
      1024, 1024, 1024, 4, 32, 1, 4096L * 1024, 1024L * 1024, 4096L * 1024);

  (void)in_sizes; (void)n_in; (void)out_size; (void)ws_size;
}